// Round 4
// baseline (34.988 us; speedup 1.0000x reference)
//
#include <hip/hip_runtime.h>

#define NG  8     // groups (heads)
#define DH  8     // channels per group
#define DHH 4     // channels per thread (half split)
#define KS  7
#define PAD 3
#define TH  16    // tile height (output rows per block)
#define TW  16    // tile width (output cols per block)
#define OW  2     // outputs per thread along W
#define TPH 22    // padded tile rows
#define TPW 22    // padded tile cols
#define LST 24    // LDS row stride in words (16B-aligned rows)
#define PLANE 532 // per-channel plane stride: 22*24 + 4 pad -> distinct bank shift per plane
#define CH  64
#define HH  64
#define WW  64

__device__ __forceinline__ int imin(int a, int b) { return a < b ? a : b; }
__device__ __forceinline__ int imax(int a, int b) { return a > b ? a : b; }

__global__ __launch_bounds__(256, 4)
void saconv_kernel(const float* __restrict__ x,
                   const float* __restrict__ wq,
                   const float* __restrict__ wk,
                   const float* __restrict__ wv,
                   const float* __restrict__ relh,
                   const float* __restrict__ relw,
                   float* __restrict__ out) {
  __shared__ float xs[DH * PLANE];      // ~17 KB padded x tile
  __shared__ float swq[DH * DH];
  __shared__ float swk[DH * DH];
  __shared__ float swv[DH * DH];
  __shared__ float srel[DH * KS];

  const int tx  = threadIdx.x;          // 0..7  (pair of output columns)
  const int tz  = threadIdx.y;          // 0..1  (channel half)
  const int ty  = threadIdx.z;          // 0..15 (output row)
  const int tid = tx + 8 * tz + 16 * ty; // 0..255 ; partner (other tz) = lane^8, same wave
  const int bz  = blockIdx.z;
  const int b   = bz >> 3;
  const int g   = bz & 7;
  const int h0  = blockIdx.y * TH;
  const int w0  = blockIdx.x * TW;

  // ---- stage weights + rel table ----
  if (tid < DH * DH) swq[tid] = wq[g * DH * DH + tid];
  else if (tid < 2 * DH * DH) swk[tid - 64] = wk[g * DH * DH + tid - 64];
  else if (tid < 3 * DH * DH) swv[tid - 128] = wv[g * DH * DH + tid - 128];
  else if (tid < 3 * DH * DH + DH * KS) {
    int t2 = tid - 192;
    int c = t2 / KS, t = t2 - c * KS;
    int gc = g * DH + c;
    srel[t2] = (g < 4) ? relh[gc * KS + t] : relw[(gc - 32) * KS + t];
  }

  // ---- stage zero-padded x tile as float4 chunks ----
  // xs[ci*PLANE + row*LST + col] = x[b, g*8+ci, h0+row-3, w0+col-3]
  const float* xb = x + (size_t)(b * CH + g * DH) * (HH * WW);
  const int NF4 = DH * TPH * 6;          // 8*22*6 = 1056 float4 chunks (cols 0..23)
  #pragma unroll
  for (int kk = 0; kk < 5; kk++) {
    int f = tid + kk * 256;
    if (f < NF4) {
      int ci  = f / (TPH * 6);
      int r   = f - ci * (TPH * 6);
      int row = r / 6;
      int c4  = r - row * 6;
      int yy  = h0 + row - PAD;
      int cy  = imin(imax(yy, 0), HH - 1);
      bool yok = (yy >= 0) & (yy < HH);
      float v[4];
      #pragma unroll
      for (int e = 0; e < 4; e++) {
        int xx = w0 + 4 * c4 + e - PAD;
        int cx = imin(imax(xx, 0), WW - 1);
        bool inb = yok & (xx >= 0) & (xx < WW);
        float t = xb[(ci * HH + cy) * WW + cx];
        v[e] = inb ? t : 0.0f;
      }
      *(float4*)(&xs[ci * PLANE + row * LST + 4 * c4]) = make_float4(v[0], v[1], v[2], v[3]);
    }
  }
  __syncthreads();

  // ---- q (full 8ch) for this thread's 2 outputs; fold into:
  //      qk[own 4 ci] = scale * (Wk^T q)   ;   rq = 0.5 * scale * (rel^T q)
  // (both halves include 0.5*rq so the shuffle-sum of partials yields full rel term)
  const float scale = 0.35355339059327373f;  // sqrt(1/8)
  const int ci0 = 4 * tz;                    // own channel base
  float qk[OW][DHH];
  float rq[OW][KS];
  {
    float q_[OW][DH];
    #pragma unroll
    for (int o = 0; o < OW; o++) {
      float xc[DH];
      #pragma unroll
      for (int ci = 0; ci < DH; ci++)
        xc[ci] = xs[ci * PLANE + (ty + PAD) * LST + 2 * tx + o + PAD];
      #pragma unroll
      for (int c = 0; c < DH; c++) {
        float a = 0.f;
        #pragma unroll
        for (int ci = 0; ci < DH; ci++)
          a = fmaf(swq[c * DH + ci], xc[ci], a);
        q_[o][c] = a;
      }
    }
    #pragma unroll
    for (int o = 0; o < OW; o++)
      #pragma unroll
      for (int n = 0; n < DHH; n++) {
        float a = 0.f;
        #pragma unroll
        for (int c = 0; c < DH; c++)
          a = fmaf(q_[o][c], swk[c * DH + ci0 + n], a);
        qk[o][n] = a * scale;
      }
    #pragma unroll
    for (int o = 0; o < OW; o++)
      #pragma unroll
      for (int t = 0; t < KS; t++) {
        float a = 0.f;
        #pragma unroll
        for (int c = 0; c < DH; c++)
          a = fmaf(q_[o][c], srel[c * KS + t], a);
        rq[o][t] = a * (0.5f * scale);
      }
  }

  // ---- window loop: half-channel partial logits, shuffle-complete, no max-shift ----
  const bool useI = (g < 4);

  float s[OW], xa[OW][DHH];
  #pragma unroll
  for (int o = 0; o < OW; o++) {
    s[o] = 0.f;
    #pragma unroll
    for (int n = 0; n < DHH; n++) xa[o][n] = 0.f;
  }

  const float* xpl = xs + ci0 * PLANE;   // own 4 planes

  #pragma unroll
  for (int i = 0; i < KS; i++) {
    const int rowoff = (ty + i) * LST + 2 * tx;   // 8B-aligned word offset
    float xr[DHH][8];
    #pragma unroll
    for (int n = 0; n < DHH; n++) {
      const float* bp = xpl + n * PLANE + rowoff;
      float2 a0 = *(const float2*)(bp);
      float2 a1 = *(const float2*)(bp + 2);
      float2 a2 = *(const float2*)(bp + 4);
      float2 a3 = *(const float2*)(bp + 6);
      xr[n][0] = a0.x; xr[n][1] = a0.y; xr[n][2] = a1.x; xr[n][3] = a1.y;
      xr[n][4] = a2.x; xr[n][5] = a2.y; xr[n][6] = a3.x; xr[n][7] = a3.y;
    }

    // partial logits over own 4 channels (each half seeds 0.5*rel)
    float d[OW][KS];
    #pragma unroll
    for (int o = 0; o < OW; o++)
      #pragma unroll
      for (int j = 0; j < KS; j++) {
        float a = useI ? rq[o][i] : rq[o][j];
        #pragma unroll
        for (int n = 0; n < DHH; n++)
          a = fmaf(qk[o][n], xr[n][o + j], a);
        d[o][j] = a;
      }

    // complete the 8-channel dot with the partner half
    #pragma unroll
    for (int o = 0; o < OW; o++)
      #pragma unroll
      for (int j = 0; j < KS; j++)
        d[o][j] += __shfl_xor(d[o][j], 8, 64);

    // exp + accumulate (exp duplicated in both halves; deterministic)
    #pragma unroll
    for (int o = 0; o < OW; o++) {
      float e[KS], se = 0.f;
      #pragma unroll
      for (int j = 0; j < KS; j++) { e[j] = __expf(d[o][j]); se += e[j]; }
      s[o] += se;
      #pragma unroll
      for (int n = 0; n < DHH; n++) {
        float a = xa[o][n];
        #pragma unroll
        for (int j = 0; j < KS; j++)
          a = fmaf(e[j], xr[n][o + j], a);
        xa[o][n] = a;
      }
    }
  }

  // ---- epilogue ----
  #pragma unroll
  for (int o = 0; o < OW; o++) {
    float inv = 1.0f / s[o];
    #pragma unroll
    for (int n = 0; n < DHH; n++) xa[o][n] *= inv;
  }

  // own-ci contributions to own-half channels and to partner-half channels
  const int cio = 4 - ci0;               // partner channel base (4*~tz)
  float po_own[OW][DHH], po_oth[OW][DHH];
  #pragma unroll
  for (int o = 0; o < OW; o++)
    #pragma unroll
    for (int n = 0; n < DHH; n++) {
      float a0 = 0.f, a1 = 0.f;
      #pragma unroll
      for (int m = 0; m < DHH; m++) {
        a0 = fmaf(swv[(ci0 + n) * DH + ci0 + m], xa[o][m], a0);  // to own c
        a1 = fmaf(swv[(cio + n) * DH + ci0 + m], xa[o][m], a1);  // to partner c
      }
      po_own[o][n] = a0;
      po_oth[o][n] = a1;
    }

  // exchange: partner's contribution to my channels
  const int h = h0 + ty;
  const int wbase = w0 + 2 * tx;
  #pragma unroll
  for (int n = 0; n < DHH; n++) {
    float2 v2;
    v2.x = po_own[0][n] + __shfl_xor(po_oth[0][n], 8, 64);
    v2.y = po_own[1][n] + __shfl_xor(po_oth[1][n], 8, 64);
    *(float2*)(&out[((size_t)(b * CH + g * DH + ci0 + n) * HH + h) * WW + wbase]) = v2;
  }
}

extern "C" void kernel_launch(void* const* d_in, const int* in_sizes, int n_in,
                              void* d_out, int out_size, void* d_ws, size_t ws_size,
                              hipStream_t stream) {
  const float* x    = (const float*)d_in[0];
  // d_in[1] = r, unused by the reference computation
  const float* wq   = (const float*)d_in[2];
  const float* wk   = (const float*)d_in[3];
  const float* wv   = (const float*)d_in[4];
  const float* relh = (const float*)d_in[5];
  const float* relw = (const float*)d_in[6];
  float* out = (float*)d_out;

  const int B = in_sizes[0] / (CH * HH * WW);   // 8
  dim3 grid(WW / TW, HH / TH, B * NG);          // 4 x 4 x 64 = 1024 blocks
  dim3 block(8, 2, 16);                         // 256 threads = 4 waves
  saconv_kernel<<<grid, block, 0, stream>>>(x, wq, wk, wv, relh, relw, out);
}

// Round 6
// 34.551 us; speedup vs baseline: 1.0126x; 1.0126x over previous
//
#include <hip/hip_runtime.h>

#define NG  8
#define DH  8
#define KS  7
#define PAD 3
#define TH  16    // tile rows
#define TW  32    // tile cols
#define CH  64
#define HH  64
#define WW  64
#define RST 80    // LDS row stride in HALVES (40 dword-cols)
#define PLH 1768  // plane stride in halves (22*80 + 8 pad)

typedef __fp16 h2 __attribute__((ext_vector_type(2)));
typedef __fp16 h4 __attribute__((ext_vector_type(4)));

__device__ __forceinline__ int imin(int a, int b) { return a < b ? a : b; }
__device__ __forceinline__ int imax(int a, int b) { return a > b ? a : b; }

__global__ __launch_bounds__(512, 4)
void saconv_kernel(const float* __restrict__ x,
                   const float* __restrict__ wq,
                   const float* __restrict__ wk,
                   const float* __restrict__ wv,
                   const float* __restrict__ relh,
                   const float* __restrict__ relw,
                   float* __restrict__ out) {
  // x tile, f16, channel-PAIR packed: xs[cp*PLH + row*RST + col*2 + p]
  // = f16(x[b, g*8 + 2*cp + p, h0+row-3, w0+col-3])
  __shared__ __fp16 xs[4 * PLH];   // ~14.2 KB

  const int tx    = threadIdx.x;     // 0..15 : pair of output columns
  const int ihalf = threadIdx.y;     // 0..1  : window-row half (i-split)
  const int ty    = threadIdx.z;     // 0..15 : output row
  const int tid   = tx + 16 * ihalf + 32 * ty;   // partner = lane^16 (same wave)
  const int bz = blockIdx.z;
  const int b  = bz >> 3;
  const int g  = bz & 7;
  const int h0 = blockIdx.y * TH;
  const int w0 = blockIdx.x * TW;

  // ---- stage zero-padded x tile (f32 global -> f16x2 ci-pair LDS) ----
  const float* xb = x + (size_t)(b * CH + g * DH) * (HH * WW);
  #pragma unroll
  for (int kk = 0; kk < 7; kk++) {
    int f = tid + kk * 512;
    if (f < 3520) {                     // 4 planes * 22 rows * 40 dword-cols
      int cp  = f / 880;
      int r   = f - cp * 880;
      int row = r / 40;
      int col = r - row * 40;
      int yy = h0 + row - PAD;
      int xx = w0 + col - PAD;
      bool inb = (yy >= 0) & (yy < HH) & (xx >= 0) & (xx < WW);
      int cy = imin(imax(yy, 0), HH - 1);
      int cx = imin(imax(xx, 0), WW - 1);
      const float* p0 = xb + ((size_t)(2 * cp) * HH + cy) * WW + cx;
      float v0 = p0[0];
      float v1 = p0[HH * WW];
      if (!inb) { v0 = 0.f; v1 = 0.f; }
      *(h2*)&xs[cp * PLH + row * RST + col * 2] = __builtin_amdgcn_cvt_pkrtz(v0, v1);
    }
  }
  __syncthreads();

  // ---- preamble: q, then fold qk = scale*Wk^T q, rq = scale*rel^T q ----
  // Weights read DIRECTLY from global with wave-uniform indices -> s_load.
  const float scale = 0.35355339059327373f;   // sqrt(1/8)
  float qk[2][DH];
  float rq[2][8];                             // [7] unused (static-index headroom)
  {
    float xc[2][DH];
    #pragma unroll
    for (int o = 0; o < 2; o++)
      #pragma unroll
      for (int ci = 0; ci < DH; ci++)
        xc[o][ci] = (float)xs[(ci >> 1) * PLH + (ty + PAD) * RST
                              + (2 * tx + o + PAD) * 2 + (ci & 1)];
    float q_[2][DH];
    #pragma unroll
    for (int o = 0; o < 2; o++)
      #pragma unroll
      for (int c = 0; c < DH; c++) {
        float a = 0.f;
        #pragma unroll
        for (int ci = 0; ci < DH; ci++)
          a = fmaf(wq[(g * DH + c) * DH + ci], xc[o][ci], a);
        q_[o][c] = a;
      }
    #pragma unroll
    for (int o = 0; o < 2; o++)
      #pragma unroll
      for (int ci = 0; ci < DH; ci++) {
        float a = 0.f;
        #pragma unroll
        for (int c = 0; c < DH; c++)
          a = fmaf(q_[o][c], wk[(g * DH + c) * DH + ci], a);
        qk[o][ci] = a * scale;
      }
    #pragma unroll
    for (int o = 0; o < 2; o++)
      #pragma unroll
      for (int t = 0; t < KS; t++) {
        float a = 0.f;
        #pragma unroll
        for (int c = 0; c < DH; c++) {
          float rv = (g < 4) ? relh[(g * DH + c) * KS + t]
                             : relw[((g - 4) * DH + c) * KS + t];
          a = fmaf(q_[o][c], rv, a);
        }
        rq[o][t] = a * scale;
      }
    rq[0][7] = 0.f; rq[1][7] = 0.f;
  }

  // ---- window loop, i-split: ihalf=0 -> i=0..3, ihalf=1 -> i=4..6 ----
  const bool useI = (g < 4);
  float s[2] = {0.f, 0.f};
  float xa[2][DH];
  #pragma unroll
  for (int o = 0; o < 2; o++)
    #pragma unroll
    for (int ci = 0; ci < DH; ci++) xa[o][ci] = 0.f;

  #pragma unroll
  for (int u = 0; u < 4; u++) {
    if (u + 4 * ihalf < KS) {
      const int row = ty + 4 * ihalf + u;
      // 8 dwords (cols 2tx..2tx+7) per channel-pair plane: 2x b64 each
      h4 xr[4][4];
      #pragma unroll
      for (int cp = 0; cp < 4; cp++) {
        const h4* rp = (const h4*)&xs[cp * PLH + row * RST + 4 * tx];
        xr[cp][0] = rp[0]; xr[cp][1] = rp[1]; xr[cp][2] = rp[2]; xr[cp][3] = rp[3];
      }
      #pragma unroll
      for (int o = 0; o < 2; o++) {
        float e[KS], se = 0.f;
        // rel term: static indices in both arms, selected by runtime ihalf
        #pragma unroll
        for (int j = 0; j < KS; j++) {
          float d = useI ? (ihalf ? rq[o][imin(4 + u, 7)] : rq[o][u]) : rq[o][j];
          #pragma unroll
          for (int ci = 0; ci < DH; ci++) {
            const int t = o + j;
            d = fmaf((float)xr[ci >> 1][t >> 1][((t & 1) << 1) | (ci & 1)],
                     qk[o][ci], d);
          }
          e[j] = __expf(d);
          se += e[j];
        }
        s[o] += se;
        #pragma unroll
        for (int ci = 0; ci < DH; ci++) {
          float a = xa[o][ci];
          #pragma unroll
          for (int j = 0; j < KS; j++) {
            const int t = o + j;
            a = fmaf(e[j], (float)xr[ci >> 1][t >> 1][((t & 1) << 1) | (ci & 1)], a);
          }
          xa[o][ci] = a;
        }
      }
    }
  }

  // ---- combine halves (single exchange; exact since no max-shift) ----
  float xav[2][DH];
  float inv[2];
  #pragma unroll
  for (int o = 0; o < 2; o++) {
    float st = s[o] + __shfl_xor(s[o], 16, 64);
    inv[o] = 1.0f / st;
  }
  #pragma unroll
  for (int o = 0; o < 2; o++)
    #pragma unroll
    for (int ci = 0; ci < DH; ci++) {
      float t_ = xa[o][ci];
      xav[o][ci] = (t_ + __shfl_xor(t_, 16, 64)) * inv[o];
    }

  // ---- epilogue: out = Wv * xav ; all 8 c computed (uniform s_load weights),
  //      each half stores its 4 channels with STATIC indices ----
  float ov[2][DH];
  #pragma unroll
  for (int o = 0; o < 2; o++)
    #pragma unroll
    for (int c = 0; c < DH; c++) {
      float a = 0.f;
      #pragma unroll
      for (int ci = 0; ci < DH; ci++)
        a = fmaf(wv[(g * DH + c) * DH + ci], xav[o][ci], a);
      ov[o][c] = a;
    }

  const int h = h0 + ty;
  const int wb = w0 + 2 * tx;
  float* ob = out + (((size_t)(b * CH + g * DH) * HH + h) * WW + wb);
  if (ihalf == 0) {
    #pragma unroll
    for (int n = 0; n < 4; n++)
      *(float2*)(ob + (size_t)n * (HH * WW)) = make_float2(ov[0][n], ov[1][n]);
  } else {
    #pragma unroll
    for (int n = 0; n < 4; n++)
      *(float2*)(ob + (size_t)(4 + n) * (HH * WW)) = make_float2(ov[0][4 + n], ov[1][4 + n]);
  }
}

extern "C" void kernel_launch(void* const* d_in, const int* in_sizes, int n_in,
                              void* d_out, int out_size, void* d_ws, size_t ws_size,
                              hipStream_t stream) {
  const float* x    = (const float*)d_in[0];
  // d_in[1] = r, unused by the reference computation
  const float* wq   = (const float*)d_in[2];
  const float* wk   = (const float*)d_in[3];
  const float* wv   = (const float*)d_in[4];
  const float* relh = (const float*)d_in[5];
  const float* relw = (const float*)d_in[6];
  float* out = (float*)d_out;

  const int B = in_sizes[0] / (CH * HH * WW);   // 8
  dim3 grid(WW / TW, HH / TH, B * NG);          // 2 x 4 x 64 = 512 blocks
  dim3 block(16, 2, 16);                        // 512 threads = 8 waves
  saconv_kernel<<<grid, block, 0, stream>>>(x, wq, wk, wv, relh, relw, out);
}